// Round 6
// baseline (3116.643 us; speedup 1.0000x reference)
//
#include <hip/hip_runtime.h>

#define NEG_INF (-3.402823466e+38f)  // -FLT_MAX

// ===================== DIAGNOSTIC 1: pure streaming read =====================
// 6 full coalesced passes over x (~6.3 GB fetched). Measures achievable
// read-only HBM BW for this exact buffer/layout. >680us so it shows in top-5.
__global__ __launch_bounds__(256) void diag_read6(const float4* __restrict__ x4,
                                                  long long n4,
                                                  float* __restrict__ ws) {
    const long long stride = (long long)gridDim.x * 256;
    float acc = 0.f;
#pragma unroll 1
    for (int pass = 0; pass < 6; ++pass) {
#pragma unroll 1
        for (long long i = (long long)blockIdx.x * 256 + threadIdx.x; i < n4; i += stride) {
            float4 a = x4[i];
            acc += a.x + a.y + a.z + a.w;
        }
    }
    // un-DCE-able sink; never true in practice, deterministic, writes only ws
    if (acc == 12345.6789f) ws[(long long)blockIdx.x * 256 + threadIdx.x] = acc;
}

// ===================== DIAGNOSTIC 2: pure selection VALU =====================
// The exact window+insert-12 inner loop on synthetic register data, ~10x the
// real kernel's selection work. Measures true VALU cost (FETCH ~ 0).
__global__ __launch_bounds__(256) void diag_valu(float* __restrict__ ws) {
    float L[12];
#pragma unroll
    for (int j = 0; j < 12; ++j) L[j] = NEG_INF;
    float h[4] = {0.f, 0.f, 0.f, 0.f};
    float w = 0.f;
    float xv = (float)threadIdx.x * 0.001f + (float)blockIdx.x * 1e-6f;

#pragma unroll 1
    for (int k = 0; k < 1250; ++k) {   // 1250 x 4 = 5000 synthetic elements
#pragma unroll
        for (int q = 0; q < 4; ++q) {  // static h indices, mirrors real kernel
            xv = fmaf(xv, 1.000001f, 0.0001f);
            w += xv - h[q];
            h[q] = xv;
            float run = w;
#pragma unroll
            for (int j = 0; j < 12; ++j) {
                float hi = fmaxf(L[j], run);
                run = fminf(L[j], run);
                L[j] = hi;
            }
        }
    }
    float s = 0.f;
#pragma unroll
    for (int j = 0; j < 12; ++j) s += L[j];
    if (s == 12345.6789f) ws[(long long)blockIdx.x * 256 + threadIdx.x] = s;
}

// ===================== REAL KERNEL: R4 (best known, 262.7 us) ================
template <int CTRL>
__device__ __forceinline__ float rormax(float v) {
    int sh = __builtin_amdgcn_update_dpp(__float_as_int(v), __float_as_int(v),
                                         CTRL, 0xF, 0xF, false);
    return fmaxf(v, __int_as_float(sh));
}

__device__ __forceinline__ float wave_max_all(float g) {
    g = rormax<0x121>(g);
    g = rormax<0x122>(g);
    g = rormax<0x124>(g);
    g = rormax<0x128>(g);
    g = fmaxf(g, __shfl_xor(g, 16, 64));
    g = fmaxf(g, __shfl_xor(g, 32, 64));
    return g;
}

__device__ __forceinline__ void win4(const float4 a, const int l, const int prevlane,
                                     float& cy, float& cz, float& cw,
                                     float& w0, float& w1, float& w2, float& w3) {
    float sy = __shfl(a.y, prevlane, 64);
    float sz = __shfl(a.z, prevlane, 64);
    float sw = __shfl(a.w, prevlane, 64);
    float p1 = (l == 0) ? cw : sw;
    float p2 = (l == 0) ? cz : sz;
    float p3 = (l == 0) ? cy : sy;
    w0 = a.x + p1 + p2 + p3;
    w1 = w0 + a.y - p3;
    w2 = w1 + a.z - p2;
    w3 = w2 + a.w - p1;
    cy = sy; cz = sz; cw = sw;
}

__global__ __launch_bounds__(256) void ssrp_wave_kernel(const float* __restrict__ x,
                                                        float* __restrict__ out) {
    __shared__ float wsum[4];
    const int t = threadIdx.x;
    const int wv = t >> 6;
    const int l = t & 63;
    const int prevlane = (l + 63) & 63;

    const long long rowBase = (long long)blockIdx.x * 128 + (long long)wv * 32;
    const float4* __restrict__ x4 = (const float4*)x;
    const float4* rowp = x4 + rowBase * 250;

    const int c3 = (192 + l <= 249) ? (192 + l) : 249;

    float4 n0 = rowp[l];
    float4 n1 = rowp[64 + l];
    float4 n2 = rowp[128 + l];
    float4 n3 = rowp[c3];

    float acc = 0.f;

#pragma unroll 1
    for (int r = 0; r < 32; ++r) {
        const float4* rp2 = (r + 1 < 32) ? (rowp + 250) : rowp;

        float v[16];
        float cy = 0.f, cz = 0.f, cw = 0.f;
        float w0, w1, w2, w3;

        win4(n0, l, prevlane, cy, cz, cw, w0, w1, w2, w3);
        {
            const bool inv = (l == 0);
            v[0] = inv ? NEG_INF : w0;
            v[1] = inv ? NEG_INF : w1;
            v[2] = inv ? NEG_INF : w2;
            v[3] = w3;
        }
        n0 = rp2[l];

        win4(n1, l, prevlane, cy, cz, cw, w0, w1, w2, w3);
        v[4] = w0; v[5] = w1; v[6] = w2; v[7] = w3;
        n1 = rp2[64 + l];

        win4(n2, l, prevlane, cy, cz, cw, w0, w1, w2, w3);
        v[8] = w0; v[9] = w1; v[10] = w2; v[11] = w3;
        n2 = rp2[128 + l];

        win4(n3, l, prevlane, cy, cz, cw, w0, w1, w2, w3);
        {
            const bool inv = (l >= 58);
            v[12] = inv ? NEG_INF : w0;
            v[13] = inv ? NEG_INF : w1;
            v[14] = inv ? NEG_INF : w2;
            v[15] = inv ? NEG_INF : w3;
        }
        n3 = rp2[c3];

#pragma unroll
        for (int k = 2; k <= 16; k <<= 1) {
#pragma unroll
            for (int j = k >> 1; j > 0; j >>= 1) {
#pragma unroll
                for (int i = 0; i < 16; ++i) {
                    const int ix = i ^ j;
                    if (ix > i) {
                        const bool up = ((i & k) == 0);
                        const float a = v[i], b = v[ix];
                        const float mx = fmaxf(a, b), mn = fminf(a, b);
                        v[i] = up ? mx : mn;
                        v[ix] = up ? mn : mx;
                    }
                }
            }
        }

        float s12 = 0.f;
#pragma unroll
        for (int rd = 0; rd < 12; ++rd) {
            const float g = wave_max_all(v[0]);
            s12 += g;
            const unsigned long long ball = __ballot(v[0] == g);
            const bool pop = (l == (int)__builtin_ctzll(ball));
#pragma unroll
            for (int i = 0; i < 11; ++i) v[i] = pop ? v[i + 1] : v[i];
        }
        acc += s12;

        rowp = rp2;
    }

    if (l == 0) wsum[wv] = acc;
    __syncthreads();
    if (t == 0)
        out[blockIdx.x] = (wsum[0] + wsum[1] + wsum[2] + wsum[3]) * (1.0f / 6144.0f);
}

extern "C" void kernel_launch(void* const* d_in, const int* in_sizes, int n_in,
                              void* d_out, int out_size, void* d_ws, size_t ws_size,
                              hipStream_t stream) {
    const float* x = (const float*)d_in[0];
    float* out = (float*)d_out;
    float* ws = (float*)d_ws;
    const long long total = (long long)in_sizes[0];  // 16*128*128*1000
    const long long n4 = total / 4;                  // float4 count
    const int rows = (int)(total / 1000);            // 262144
    const int blocks = rows / 128;                   // 2048 == out_size

    // diagnostics first (sized to beat the ~640us fill dispatches into top-5)
    hipLaunchKernelGGL(diag_read6, dim3(2048), dim3(256), 0, stream,
                       (const float4*)x, n4, ws);
    hipLaunchKernelGGL(diag_valu, dim3(2048), dim3(256), 0, stream, ws);

    // real kernel (R4, unchanged)
    hipLaunchKernelGGL(ssrp_wave_kernel, dim3(blocks), dim3(256), 0, stream, x, out);
}

// Round 7
// 257.364 us; speedup vs baseline: 12.1098x; 12.1098x over previous
//
#include <hip/hip_runtime.h>

#define NEG_INF (-3.402823466e+38f)  // -FLT_MAX

// Insert candidate v into sorted-descending top-12 list L.
// Identity: new L[j] = max(L[j], min(L[j-1], v)) == med3(v, L[j-1], L[j])
// (valid because L[j-1] >= L[j]). One VALU op per level, all independent.
__device__ __forceinline__ void insert12(float L[12], const float v) {
    const float p0 = L[0], p1 = L[1], p2 = L[2], p3 = L[3], p4 = L[4],
                p5 = L[5], p6 = L[6], p7 = L[7], p8 = L[8], p9 = L[9],
                p10 = L[10];
    L[0] = fmaxf(p0, v);
    L[1] = __builtin_amdgcn_fmed3f(v, p0, p1);
    L[2] = __builtin_amdgcn_fmed3f(v, p1, p2);
    L[3] = __builtin_amdgcn_fmed3f(v, p2, p3);
    L[4] = __builtin_amdgcn_fmed3f(v, p3, p4);
    L[5] = __builtin_amdgcn_fmed3f(v, p4, p5);
    L[6] = __builtin_amdgcn_fmed3f(v, p5, p6);
    L[7] = __builtin_amdgcn_fmed3f(v, p6, p7);
    L[8] = __builtin_amdgcn_fmed3f(v, p7, p8);
    L[9] = __builtin_amdgcn_fmed3f(v, p8, p9);
    L[10] = __builtin_amdgcn_fmed3f(v, p9, p10);
    L[11] = __builtin_amdgcn_fmed3f(v, p10, L[11]);
}

// Process 16 consecutive row elements (4 float4 regs): update running
// window-4 sum, med3-insert each completed window. KLO: first valid element.
template <int KLO>
__device__ __forceinline__ void proc16(const float4 a, const float4 b,
                                       const float4 c, const float4 d,
                                       float h[4], float& w, float L[12]) {
    float xs[16];
    xs[0] = a.x;  xs[1] = a.y;  xs[2] = a.z;  xs[3] = a.w;
    xs[4] = b.x;  xs[5] = b.y;  xs[6] = b.z;  xs[7] = b.w;
    xs[8] = c.x;  xs[9] = c.y;  xs[10] = c.z; xs[11] = c.w;
    xs[12] = d.x; xs[13] = d.y; xs[14] = d.z; xs[15] = d.w;
#pragma unroll
    for (int k = 0; k < 16; ++k) {
        float xv = xs[k];
        w += xv - h[k & 3];   // running 4-window sum (/W folded into epilogue)
        h[k & 3] = xv;        // static index after unroll
        if (k >= KLO) insert12(L, w);
    }
}

// Tail: 8 elements (2 float4s), all windows valid.
__device__ __forceinline__ void proc8(const float4 a, const float4 b,
                                      float h[4], float& w, float L[12]) {
    float xs[8];
    xs[0] = a.x; xs[1] = a.y; xs[2] = a.z; xs[3] = a.w;
    xs[4] = b.x; xs[5] = b.y; xs[6] = b.z; xs[7] = b.w;
#pragma unroll
    for (int k = 0; k < 8; ++k) {
        float xv = xs[k];
        w += xv - h[k & 3];
        h[k & 3] = xv;
        insert12(L, w);
    }
}

// Thread-per-row, direct global loads (no LDS staging, no hot-loop barriers,
// no cross-lane ops in compute). Each thread streams its 4000 B row in 64 B
// chunks; a thread's 4 consecutive float4s share a cache line, so HBM traffic
// is exactly 1x. Block = 256 threads = 256 rows = 2 outputs.
__global__ __launch_bounds__(256) void ssrp_tpr_kernel(const float* __restrict__ x,
                                                       float* __restrict__ out) {
    __shared__ float wsum[4];
    const int t = threadIdx.x;
    const long long row = (long long)blockIdx.x * 256 + t;
    const float4* __restrict__ p = (const float4*)x + row * 250;

    float L[12];
#pragma unroll
    for (int j = 0; j < 12; ++j) L[j] = NEG_INF;
    float h[4] = {0.f, 0.f, 0.f, 0.f};
    float w = 0.f;

    // depth-2 software pipeline: chunks s (a), s+1 (b) in regs, s+2 loading
    float4 a0 = p[0], a1 = p[1], a2 = p[2], a3 = p[3];
    float4 b0 = p[4], b1 = p[5], b2 = p[6], b3 = p[7];
    p += 8;

    // chunk 0: elements 0..15; first valid window ends at element 3
    proc16<3>(a0, a1, a2, a3, h, w, L);
    a0 = b0; a1 = b1; a2 = b2; a3 = b3;

#pragma unroll 1
    for (int s = 1; s < 61; ++s) {
        b0 = p[0]; b1 = p[1]; b2 = p[2]; b3 = p[3];  // prefetch chunk s+2
        p += 4;
        proc16<0>(a0, a1, a2, a3, h, w, L);          // process chunk s
        a0 = b0; a1 = b1; a2 = b2; a3 = b3;
    }

    // chunk 61 prefetched; tail = cols 248,249 (elements 992..999)
    b0 = p[0]; b1 = p[1];
    proc16<0>(a0, a1, a2, a3, h, w, L);
    proc8(b0, b1, h, w, L);

    // sum of top-12 window sums for this row
    float s12 = 0.f;
#pragma unroll
    for (int j = 0; j < 12; ++j) s12 += L[j];

    // wave reduce: all 64 threads of a wave belong to the same output entry
#pragma unroll
    for (int off = 1; off < 64; off <<= 1) s12 += __shfl_xor(s12, off, 64);

    if ((t & 63) == 0) wsum[t >> 6] = s12;
    __syncthreads();

    // out = sum over 128 rows / (W=4 * K=12 * F=128); written exactly once
    if (t == 0) out[blockIdx.x * 2 + 0] = (wsum[0] + wsum[1]) * (1.0f / 6144.0f);
    if (t == 128) out[blockIdx.x * 2 + 1] = (wsum[2] + wsum[3]) * (1.0f / 6144.0f);
}

extern "C" void kernel_launch(void* const* d_in, const int* in_sizes, int n_in,
                              void* d_out, int out_size, void* d_ws, size_t ws_size,
                              hipStream_t stream) {
    const float* x = (const float*)d_in[0];
    float* out = (float*)d_out;
    const long long total = (long long)in_sizes[0];  // 16*128*128*1000
    const int rows = (int)(total / 1000);            // 262144
    const int blocks = rows / 256;                   // 1024 (= out_size/2)
    hipLaunchKernelGGL(ssrp_tpr_kernel, dim3(blocks), dim3(256), 0, stream, x, out);
}

// Round 8
// 202.199 us; speedup vs baseline: 15.4138x; 1.2728x over previous
//
#include <hip/hip_runtime.h>

#define NEG_INF (-3.402823466e+38f)  // -FLT_MAX

// quad_perm DPP (VALU pipe). CTRL = quad_perm selector byte.
template <int CTRL>
__device__ __forceinline__ float qperm(float v) {
    return __int_as_float(__builtin_amdgcn_update_dpp(
        __float_as_int(v), __float_as_int(v), CTRL, 0xF, 0xF, false));
}
// 0x90 = [0,0,1,2]: lane q gets lane q-1's value (q>=1); 0xFF = bcast lane 3
// 0xB1 = [1,0,3,2]: xor1 swap; 0x4E = [2,3,0,1]: xor2 swap

// Insert v into sorted-descending top-12 L. new L[j] = med3(v, L[j-1], L[j]).
__device__ __forceinline__ void insert12(float L[12], const float v) {
    const float p0 = L[0], p1 = L[1], p2 = L[2], p3 = L[3], p4 = L[4],
                p5 = L[5], p6 = L[6], p7 = L[7], p8 = L[8], p9 = L[9],
                p10 = L[10];
    L[0] = fmaxf(p0, v);
    L[1] = __builtin_amdgcn_fmed3f(v, p0, p1);
    L[2] = __builtin_amdgcn_fmed3f(v, p1, p2);
    L[3] = __builtin_amdgcn_fmed3f(v, p2, p3);
    L[4] = __builtin_amdgcn_fmed3f(v, p3, p4);
    L[5] = __builtin_amdgcn_fmed3f(v, p4, p5);
    L[6] = __builtin_amdgcn_fmed3f(v, p5, p6);
    L[7] = __builtin_amdgcn_fmed3f(v, p6, p7);
    L[8] = __builtin_amdgcn_fmed3f(v, p7, p8);
    L[9] = __builtin_amdgcn_fmed3f(v, p8, p9);
    L[10] = __builtin_amdgcn_fmed3f(v, p9, p10);
    L[11] = __builtin_amdgcn_fmed3f(v, p10, L[11]);
}

// Process one chunk: lane holds float4 a = its 4 consecutive elements of its
// row. Prev-3 elements come from lane q-1 via quad_perm (q>=1) or carry (q==0,
// = prev chunk's lane-3 values). MODE: 0=first chunk, 1=mid, 2=tail.
template <int MODE>
__device__ __forceinline__ void chunk(const float4 a, const int q,
                                      float& cy, float& cz, float& cw,
                                      float L[12]) {
    const float dy = qperm<0x90>(a.y);
    const float dz = qperm<0x90>(a.z);
    const float dw = qperm<0x90>(a.w);
    const bool q0 = (q == 0);
    const float p1 = q0 ? cw : dw;  // element e-1
    const float p2 = q0 ? cz : dz;  // element e-2
    const float p3 = q0 ? cy : dy;  // element e-3
    float w0 = a.x + p1 + p2 + p3;
    float w1 = w0 + a.y - p3;
    float w2 = w1 + a.z - p2;
    float w3 = w2 + a.w - p1;
    if (MODE == 0) {  // windows at e=0,1,2 invalid (lane q==0 only)
        w0 = q0 ? NEG_INF : w0;
        w1 = q0 ? NEG_INF : w1;
        w2 = q0 ? NEG_INF : w2;
    }
    if (MODE == 2) {  // elements 1000..1007 invalid (lanes q>=2)
        const bool inv = (q >= 2);
        w0 = inv ? NEG_INF : w0;
        w1 = inv ? NEG_INF : w1;
        w2 = inv ? NEG_INF : w2;
        w3 = inv ? NEG_INF : w3;
    }
    // carry for next chunk's q==0 lane: this chunk's lane-3 y,z,w
    cy = qperm<0xFF>(a.y);
    cz = qperm<0xFF>(a.z);
    cw = qperm<0xFF>(a.w);
    insert12(L, w0);
    insert12(L, w1);
    insert12(L, w2);
    insert12(L, w3);
}

// 4 lanes per row, 16 rows per wave, 8 waves per block -> 128 rows = 1 output.
// Wave load instr touches 16 cache lines (coalesced-grade); occupancy 4x the
// thread-per-row layout; no DS ops in the hot loop (all cross-lane via DPP).
__global__ __launch_bounds__(512) void ssrp_quad_kernel(const float* __restrict__ x,
                                                        float* __restrict__ out) {
    __shared__ float wsum[8];
    const int t = threadIdx.x;
    const int wv = t >> 6;
    const int l = t & 63;
    const int q = l & 3;

    const long long row = (long long)blockIdx.x * 128 + wv * 16 + (l >> 2);
    const float4* __restrict__ pr = (const float4*)x + row * 250;

    float L[12];
#pragma unroll
    for (int j = 0; j < 12; ++j) L[j] = NEG_INF;
    float cy = 0.f, cz = 0.f, cw = 0.f;

    // chunk s covers elements 16s..16s+15; lane's float4 index = 4s+q (<=249)
    float4 a = pr[q];        // chunk 0
    float4 b = pr[4 + q];    // chunk 1
    {
        float4 nb = pr[8 + q];               // chunk 2
        chunk<0>(a, q, cy, cz, cw, L);
        a = b; b = nb;
    }
#pragma unroll 2
    for (int s = 1; s <= 60; ++s) {
        int off = (s + 2) * 4 + q;           // chunk s+2; max 251 at s=60
        off = off < 249 ? off : 249;         // clamp tail lanes (masked later)
        float4 nb = pr[off];
        chunk<1>(a, q, cy, cz, cw, L);       // process chunk s
        a = b; b = nb;
    }
    chunk<1>(a, q, cy, cz, cw, L);           // chunk 61 (all valid)
    chunk<2>(b, q, cy, cz, cw, L);           // chunk 62 (tail: e 992..999)

    // ---- merge the 4 sorted per-lane lists: 12-round quad max-extraction
    float s12 = 0.f;
#pragma unroll
    for (int rd = 0; rd < 12; ++rd) {
        const float h = L[0];
        float g = fmaxf(h, qperm<0xB1>(h));
        g = fmaxf(g, qperm<0x4E>(g));        // quad max, same in all 4 lanes
        s12 += g;
        const unsigned long long ball = __ballot(h == g);
        const unsigned qm = (unsigned)(ball >> (l & ~3)) & 0xFu;
        const bool pop = (q == (int)__builtin_ctz(qm));  // unique winner
#pragma unroll
        for (int i = 0; i < 11; ++i) L[i] = pop ? L[i + 1] : L[i];
        L[11] = pop ? NEG_INF : L[11];
    }

    // s12 identical across the 4 lanes of a quad; take q==0 reps, wave-sum
    float contrib = (q == 0) ? s12 : 0.f;
    contrib += __shfl_xor(contrib, 4, 64);
    contrib += __shfl_xor(contrib, 8, 64);
    contrib += __shfl_xor(contrib, 16, 64);
    contrib += __shfl_xor(contrib, 32, 64);
    if (l == 0) wsum[wv] = contrib;
    __syncthreads();

    if (t == 0) {
        float s = 0.f;
#pragma unroll
        for (int i = 0; i < 8; ++i) s += wsum[i];
        out[blockIdx.x] = s * (1.0f / 6144.0f);  // / (W*K*F)
    }
}

extern "C" void kernel_launch(void* const* d_in, const int* in_sizes, int n_in,
                              void* d_out, int out_size, void* d_ws, size_t ws_size,
                              hipStream_t stream) {
    const float* x = (const float*)d_in[0];
    float* out = (float*)d_out;
    const long long total = (long long)in_sizes[0];  // 16*128*128*1000
    const int rows = (int)(total / 1000);            // 262144
    const int blocks = rows / 128;                   // 2048 == out_size
    hipLaunchKernelGGL(ssrp_quad_kernel, dim3(blocks), dim3(512), 0, stream, x, out);
}